// Round 2
// baseline (437.929 us; speedup 1.0000x reference)
//
#include <hip/hip_runtime.h>
#include <hip/hip_bf16.h>
#include <stdint.h>

// Problem constants (fixed by reference setup_inputs)
#define NX 16384   // rows of x
#define NC 4096    // rows of prototype (= output cols)
#define DIM 1024   // feature dim (K)

typedef __attribute__((ext_vector_type(8))) short bf16x8;   // 4 VGPRs, 8 bf16
typedef __attribute__((ext_vector_type(4))) float f32x4;    // 4 VGPRs

// ---------- helpers ----------

__device__ inline unsigned short f2bf_rn(float f) {
  union { float f; unsigned u; } v; v.f = f;
  unsigned u = v.u;
  unsigned r = (u + 0x7FFFu + ((u >> 16) & 1u)) >> 16;  // round-nearest-even
  return (unsigned short)r;
}

__device__ inline void gload_lds16(const void* g, const void* l) {
  // width-16 direct global->LDS. LDS dest = wave-uniform base + lane*16 (linear).
  __builtin_amdgcn_global_load_lds(
      (const __attribute__((address_space(1))) void*)g,
      (__attribute__((address_space(3))) void*)l,
      16, 0, 0);
}

__device__ inline f32x4 mfma_bf16_16x16x32(bf16x8 a, bf16x8 b, f32x4 c) {
  // inline asm: signature-proof vs builtin short8/bf16x8 ambiguity.
  // gfx950 unified VGPR/AGPR file: v[] operands are valid for MFMA.
  asm("v_mfma_f32_16x16x32_bf16 %0, %1, %2, %0" : "+v"(c) : "v"(a), "v"(b));
  return c;
}

// ---------- kernel 1: fp32 -> bf16 + fp32 row sum-of-squares ----------
// one block (256 thr) per row of DIM=1024: each thread handles one float4.

__global__ __launch_bounds__(256) void convert_rows(
    const float* __restrict__ src, unsigned short* __restrict__ dst,
    float* __restrict__ sq) {
  __shared__ float red[4];
  const int row = blockIdx.x;
  const int tid = threadIdx.x;
  const size_t base = (size_t)row * DIM + tid * 4;

  const float4 v = *(const float4*)(src + base);
  float s = v.x * v.x + v.y * v.y + v.z * v.z + v.w * v.w;

  ushort4 o;
  o.x = f2bf_rn(v.x); o.y = f2bf_rn(v.y);
  o.z = f2bf_rn(v.z); o.w = f2bf_rn(v.w);
  *(ushort4*)(dst + base) = o;

  // wave64 shuffle reduce, then cross-wave via LDS
  #pragma unroll
  for (int off = 32; off > 0; off >>= 1) s += __shfl_down(s, off, 64);
  const int lane = tid & 63, w = tid >> 6;
  if (lane == 0) red[w] = s;
  __syncthreads();
  if (tid == 0) sq[row] = red[0] + red[1] + red[2] + red[3];
}

// ---------- kernel 2: bf16 MFMA GEMM + distance epilogue ----------
// m97 structure: BM=BN=128, BK=32, 256 threads = 4 waves (2x2), each wave
// owns a 64x64 output sub-tile = 4x4 fragments of 16x16, K-loop of 32 steps.

#define BM 128
#define BN 128
#define BK 32

__global__ __launch_bounds__(256, 2) void dist_gemm(
    const unsigned short* __restrict__ xb,   // [NX][DIM] bf16
    const unsigned short* __restrict__ pb,   // [NC][DIM] bf16
    const float* __restrict__ xsq,           // [NX]
    const float* __restrict__ psq,           // [NC]
    float* __restrict__ out) {               // [NX][NC]
  __shared__ short As[BM * BK];   // 8 KB, row-major [row][k]
  __shared__ short Bs[BN * BK];   // 8 KB, row-major [col(c)][k]

  const int tid  = threadIdx.x;
  const int w    = tid >> 6;
  const int lane = tid & 63;
  const int bm = blockIdx.y * BM;   // x-row base
  const int bn = blockIdx.x * BN;   // prototype base

  // staging: wave w stages 1KB chunks {w, w+4} of each tile.
  // chunk c = rows [16c,16c+16); lane l -> row 16c + l/4, k-chunk (l&3)*8.
  // LDS linear check: (l>>2)*32 + (l&3)*8 == 8*l  (hardware writes base+lane*16B). OK.
  const int srow = lane >> 2;
  const int skc  = (lane & 3) * 8;

  // compute-side fragment coords
  const int wr = (w >> 1) * 64;        // wave row base in tile
  const int wc = (w & 1) * 64;         // wave col base in tile
  const int fr = lane & 15;            // A-row / B-col within fragment
  const int fk = (lane >> 4) * 8;      // k offset within fragment (elems)

  f32x4 acc[4][4] = {};

  const unsigned short* gA0 = xb + (size_t)(bm + w * 16 + srow) * DIM + skc;
  const unsigned short* gA1 = xb + (size_t)(bm + (w + 4) * 16 + srow) * DIM + skc;
  const unsigned short* gB0 = pb + (size_t)(bn + w * 16 + srow) * DIM + skc;
  const unsigned short* gB1 = pb + (size_t)(bn + (w + 4) * 16 + srow) * DIM + skc;
  short* lA0 = &As[(w * 16) * BK];
  short* lA1 = &As[((w + 4) * 16) * BK];
  short* lB0 = &Bs[(w * 16) * BK];
  short* lB1 = &Bs[((w + 4) * 16) * BK];

  for (int k0 = 0; k0 < DIM; k0 += BK) {
    gload_lds16(gA0 + k0, lA0);
    gload_lds16(gA1 + k0, lA1);
    gload_lds16(gB0 + k0, lB0);
    gload_lds16(gB1 + k0, lB1);
    __syncthreads();   // drains vmcnt(0): LDS tiles ready

    bf16x8 a[4], b[4];
    #pragma unroll
    for (int i = 0; i < 4; ++i)
      a[i] = *(const bf16x8*)&As[(wr + i * 16 + fr) * BK + fk];
    #pragma unroll
    for (int j = 0; j < 4; ++j)
      b[j] = *(const bf16x8*)&Bs[(wc + j * 16 + fr) * BK + fk];

    #pragma unroll
    for (int i = 0; i < 4; ++i)
      #pragma unroll
      for (int j = 0; j < 4; ++j)
        acc[i][j] = mfma_bf16_16x16x32(a[i], b[j], acc[i][j]);

    __syncthreads();   // all waves done reading before next stage overwrites
  }

  // epilogue: d = xsq[r] + psq[c] - 2*cross
  // C/D layout (m89-verified): reg i -> row (lane>>4)*4 + i, col lane&15.
  float pv[4];
  #pragma unroll
  for (int j = 0; j < 4; ++j) pv[j] = psq[bn + wc + j * 16 + fr];

  #pragma unroll
  for (int i = 0; i < 4; ++i) {
    #pragma unroll
    for (int ri = 0; ri < 4; ++ri) {
      const int r = bm + wr + i * 16 + (lane >> 4) * 4 + ri;
      const float xv = xsq[r];
      #pragma unroll
      for (int j = 0; j < 4; ++j) {
        const int c = bn + wc + j * 16 + fr;
        out[(size_t)r * NC + c] = xv + pv[j] - 2.0f * acc[i][j][ri];
      }
    }
  }
}

// ---------- launch ----------

extern "C" void kernel_launch(void* const* d_in, const int* in_sizes, int n_in,
                              void* d_out, int out_size, void* d_ws, size_t ws_size,
                              hipStream_t stream) {
  const float* x = (const float*)d_in[0];   // [16384][1024] fp32
  const float* p = (const float*)d_in[1];   // [4096][1024] fp32
  float* out = (float*)d_out;               // [16384][4096] fp32

  // workspace layout (40.1 MB total)
  char* ws = (char*)d_ws;
  unsigned short* xb  = (unsigned short*)ws;                         // 32 MB
  unsigned short* pbb = (unsigned short*)(ws + (size_t)NX * DIM * 2); // 8 MB
  float* xsq = (float*)(ws + (size_t)NX * DIM * 2 + (size_t)NC * DIM * 2);
  float* psq = xsq + NX;

  convert_rows<<<NX, 256, 0, stream>>>(x, xb, xsq);
  convert_rows<<<NC, 256, 0, stream>>>(p, pbb, psq);

  dim3 grid(NC / BN, NX / BM);  // (32, 128)
  dist_gemm<<<grid, dim3(256, 1, 1), 0, stream>>>(xb, pbb, xsq, psq, out);
}